// Round 2
// baseline (2014.145 us; speedup 1.0000x reference)
//
#include <hip/hip_runtime.h>
#include <hip/hip_bf16.h>

#define U_CNT 100000
#define I_CNT 50000
#define N_CNT 150000   // U + I
#define K_DIM 64
#define E_CNT 500000
#define F_DIM 64
#define N_LAYERS 3
#define B_CNT 100000

// --- degree count: deg[rows[e]] += 1; deg[cols[e]] += 1 ---------------------
__global__ __launch_bounds__(256) void deg_kernel(const int* __restrict__ rows,
                                                  const int* __restrict__ cols,
                                                  float* __restrict__ deg) {
    int e = blockIdx.x * blockDim.x + threadIdx.x;
    if (e < E_CNT) {
        atomicAdd(&deg[rows[e]], 1.0f);
        atomicAdd(&deg[cols[e]], 1.0f);
    }
}

// --- dinv in place: deg -> rsqrt(deg) or 0 ----------------------------------
__global__ __launch_bounds__(256) void dinv_kernel(float* __restrict__ deg) {
    int n = blockIdx.x * blockDim.x + threadIdx.x;
    if (n < N_CNT) {
        float d = deg[n];
        deg[n] = (d > 0.0f) ? rsqrtf(d) : 0.0f;
    }
}

// --- per-undirected-edge norm: dinv[r]*dinv[c] ------------------------------
__global__ __launch_bounds__(256) void nrm_kernel(const int* __restrict__ rows,
                                                  const int* __restrict__ cols,
                                                  const float* __restrict__ dinv,
                                                  float* __restrict__ nrm) {
    int e = blockIdx.x * blockDim.x + threadIdx.x;
    if (e < E_CNT) {
        nrm[e] = dinv[rows[e]] * dinv[cols[e]];
    }
}

// --- edge projection: ep = edge_features @ W + b  (E x 64, fp32) ------------
// One wave handles 16 edges; lane k owns output column k. The edge row is
// broadcast lane->lane via __shfl (register path, no LDS write->read hazard).
// W staged once per block in LDS; sW[f][0..63] read by 64 lanes over 32 banks
// = 2 lanes/bank = conflict-free.
__global__ __launch_bounds__(256) void ep_kernel(const float* __restrict__ ef,
                                                 const float* __restrict__ W,
                                                 const float* __restrict__ bias,
                                                 float* __restrict__ ep) {
    __shared__ float sW[F_DIM][K_DIM + 1];
    int tid = threadIdx.x;
    for (int idx = tid; idx < F_DIM * K_DIM; idx += 256) {
        sW[idx >> 6][idx & 63] = W[idx];
    }
    __syncthreads();
    int k = tid & 63;
    int wv = tid >> 6;
    float bv = bias[k];
    int eb = blockIdx.x * 64 + wv * 16;
    for (int c = 0; c < 16; c++) {
        int e = eb + c;
        if (e >= E_CNT) break;
        float rv = ef[e * F_DIM + k];   // lane k holds row element f=k
        float acc = bv;
        #pragma unroll
        for (int f = 0; f < F_DIM; f++) {
            acc += __shfl(rv, f, 64) * sW[f][k];
        }
        ep[e * K_DIM + k] = acc;
    }
}

// --- init fp32 tables: C = concat(Gu,Gi), T = concat(Gut,Git) ---------------
__global__ __launch_bounds__(256) void init_kernel(const float* __restrict__ Gu,
                                                   const float* __restrict__ Gi,
                                                   const float* __restrict__ Gut,
                                                   const float* __restrict__ Git,
                                                   float* __restrict__ C,
                                                   float* __restrict__ T) {
    int idx = blockIdx.x * blockDim.x + threadIdx.x;
    const int UK = U_CNT * K_DIM;
    const int NK = N_CNT * K_DIM;
    if (idx < NK) {
        if (idx < UK) {
            C[idx] = Gu[idx];
            T[idx] = Gut[idx];
        } else {
            C[idx] = Gi[idx - UK];
            T[idx] = Git[idx - UK];
        }
    }
}

// --- one propagation layer: wave per undirected edge, lane per feature ------
// collab_out[d] += collab_in[s]*nrm ; textual_out[d] += textual_in[s]*ep*nrm
// for both directions (r->c, c->r); ep2 = concat(ep,ep) so both reuse ep[j].
__global__ __launch_bounds__(256) void prop_kernel(const int* __restrict__ rows,
                                                   const int* __restrict__ cols,
                                                   const float* __restrict__ nrm,
                                                   const float* __restrict__ ep,
                                                   const float* __restrict__ Cin,
                                                   const float* __restrict__ Tin,
                                                   float* __restrict__ Cout,
                                                   float* __restrict__ Tout) {
    int gt = blockIdx.x * blockDim.x + threadIdx.x;
    int j = gt >> 6;
    int k = threadIdx.x & 63;
    if (j >= E_CNT) return;
    int r = rows[j];
    int c = cols[j];
    float w = nrm[j];
    float e = ep[j * K_DIM + k] * w;
    int ri = r * K_DIM + k;
    int ci = c * K_DIM + k;
    float cr = Cin[ri];
    float cc = Cin[ci];
    float tr = Tin[ri];
    float tc = Tin[ci];
    atomicAdd(&Cout[ci], cr * w);
    atomicAdd(&Cout[ri], cc * w);
    atomicAdd(&Tout[ci], tr * e);
    atomicAdd(&Tout[ri], tc * e);
}

// --- scoring: wave per query, 64-lane shuffle reduction ---------------------
__global__ __launch_bounds__(256) void score_kernel(const int* __restrict__ users,
                                                    const int* __restrict__ items,
                                                    const float* __restrict__ C,
                                                    const float* __restrict__ T,
                                                    const float* __restrict__ Bu,
                                                    const float* __restrict__ Bi,
                                                    const float* __restrict__ But,
                                                    const float* __restrict__ Bit,
                                                    const float* __restrict__ Mu,
                                                    float* __restrict__ out) {
    int gt = blockIdx.x * blockDim.x + threadIdx.x;
    int b = gt >> 6;
    int k = threadIdx.x & 63;
    if (b >= B_CNT) return;
    int u = users[b];
    int it = items[b];
    int ui = u * K_DIM + k;
    int ii = (U_CNT + it) * K_DIM + k;
    float v = C[ui] * C[ii] + T[ui] * T[ii];
    #pragma unroll
    for (int off = 32; off > 0; off >>= 1) {
        v += __shfl_down(v, off, 64);
    }
    if (k == 0) {
        v += Bu[u] + Bi[it] + But[u] + Bit[it] + Mu[0];
        out[b] = v;
    }
}

extern "C" void kernel_launch(void* const* d_in, const int* in_sizes, int n_in,
                              void* d_out, int out_size, void* d_ws, size_t ws_size,
                              hipStream_t stream) {
    const float* Gu   = (const float*)d_in[0];
    const float* Gi   = (const float*)d_in[1];
    const float* Gut  = (const float*)d_in[2];
    const float* Git  = (const float*)d_in[3];
    const float* Bu   = (const float*)d_in[4];
    const float* Bi   = (const float*)d_in[5];
    const float* But  = (const float*)d_in[6];
    const float* Bit  = (const float*)d_in[7];
    const float* Mu   = (const float*)d_in[8];
    const float* W    = (const float*)d_in[9];
    const float* bpj  = (const float*)d_in[10];
    const float* ef   = (const float*)d_in[11];
    const int* rows   = (const int*)d_in[12];
    const int* cols   = (const int*)d_in[13];
    const int* users  = (const int*)d_in[14];
    const int* items  = (const int*)d_in[15];
    float* out = (float*)d_out;

    const size_t NK = (size_t)N_CNT * K_DIM;
    float* ws  = (float*)d_ws;
    float* deg = ws;                              // N
    float* nrm = deg + N_CNT;                     // E
    float* ep  = nrm + E_CNT;                     // E*K   (128 MB)
    float* C0  = ep + (size_t)E_CNT * K_DIM;      // N*K   (38.4 MB)
    float* C1  = C0 + NK;
    float* T0  = C1 + NK;
    float* T1  = T0 + NK;
    // total ~284 MB of d_ws

    hipMemsetAsync(deg, 0, N_CNT * sizeof(float), stream);
    deg_kernel<<<(E_CNT + 255) / 256, 256, 0, stream>>>(rows, cols, deg);
    dinv_kernel<<<(N_CNT + 255) / 256, 256, 0, stream>>>(deg);
    nrm_kernel<<<(E_CNT + 255) / 256, 256, 0, stream>>>(rows, cols, deg, nrm);
    ep_kernel<<<(E_CNT + 63) / 64, 256, 0, stream>>>(ef, W, bpj, ep);
    init_kernel<<<((int)NK + 255) / 256, 256, 0, stream>>>(Gu, Gi, Gut, Git, C0, T0);

    float* Cs[2] = {C0, C1};
    float* Ts[2] = {T0, T1};
    int cur = 0;
    for (int l = 0; l < N_LAYERS; l++) {
        float* Cin  = Cs[cur];
        float* Tin  = Ts[cur];
        float* Cout = Cs[1 - cur];
        float* Tout = Ts[1 - cur];
        hipMemsetAsync(Cout, 0, NK * sizeof(float), stream);
        hipMemsetAsync(Tout, 0, NK * sizeof(float), stream);
        prop_kernel<<<(E_CNT * 64 + 255) / 256, 256, 0, stream>>>(
            rows, cols, nrm, ep, Cin, Tin, Cout, Tout);
        cur = 1 - cur;
    }

    score_kernel<<<(B_CNT * 64 + 255) / 256, 256, 0, stream>>>(
        users, items, Cs[cur], Ts[cur], Bu, Bi, But, Bit, Mu, out);
}

// Round 3
// 1280.988 us; speedup vs baseline: 1.5723x; 1.5723x over previous
//
#include <hip/hip_runtime.h>
#include <hip/hip_bf16.h>

#define U_CNT 100000
#define I_CNT 50000
#define N_CNT 150000   // U + I
#define K_DIM 64
#define E_CNT 500000
#define F_DIM 64
#define N_LAYERS 3
#define B_CNT 100000
#define SCAN_T 1024

// --- int degree count over both endpoints -----------------------------------
__global__ __launch_bounds__(256) void cnt_kernel(const int* __restrict__ rows,
                                                  const int* __restrict__ cols,
                                                  int* __restrict__ cnt) {
    int e = blockIdx.x * blockDim.x + threadIdx.x;
    if (e < E_CNT) {
        atomicAdd(&cnt[rows[e]], 1);
        atomicAdd(&cnt[cols[e]], 1);
    }
}

// --- dinv[n] = deg>0 ? rsqrt(deg) : 0 ---------------------------------------
__global__ __launch_bounds__(256) void dinv_kernel(const int* __restrict__ cnt,
                                                   float* __restrict__ dinv) {
    int n = blockIdx.x * blockDim.x + threadIdx.x;
    if (n < N_CNT) {
        int c = cnt[n];
        dinv[n] = (c > 0) ? rsqrtf((float)c) : 0.0f;
    }
}

// --- single-block exclusive scan of cnt -> offs (and cursor copy) -----------
__global__ __launch_bounds__(SCAN_T) void scan_kernel(const int* __restrict__ cnt,
                                                      int* __restrict__ offs,
                                                      int* __restrict__ cursor) {
    __shared__ int sd[SCAN_T];
    int tid = threadIdx.x;
    const int chunk = (N_CNT + SCAN_T - 1) / SCAN_T;   // 147
    int base = tid * chunk;
    int end = min(base + chunk, N_CNT);
    int s = 0;
    for (int i = base; i < end; i++) s += cnt[i];
    sd[tid] = s;
    __syncthreads();
    for (int off = 1; off < SCAN_T; off <<= 1) {
        int v = 0;
        if (tid >= off) v = sd[tid - off];
        __syncthreads();
        if (tid >= off) sd[tid] += v;
        __syncthreads();
    }
    int running = (tid > 0) ? sd[tid - 1] : 0;
    for (int i = base; i < end; i++) {
        offs[i] = running;
        cursor[i] = running;
        running += cnt[i];
    }
    if (tid == SCAN_T - 1) offs[N_CNT] = 2 * E_CNT;
}

// --- scatter directed edges into CSR slots ----------------------------------
// directed edge d: d<E -> (src=rows, dst=cols), else (src=cols, dst=rows).
// Slot order nondeterministic (atomic cursor) — only perturbs fp sum order.
__global__ __launch_bounds__(256) void scatter_kernel(const int* __restrict__ rows,
                                                      const int* __restrict__ cols,
                                                      const float* __restrict__ dinv,
                                                      int* __restrict__ cursor,
                                                      int* __restrict__ esrc,
                                                      int* __restrict__ eeid,
                                                      float* __restrict__ wvals) {
    int d = blockIdx.x * blockDim.x + threadIdx.x;
    if (d >= 2 * E_CNT) return;
    int eid = (d < E_CNT) ? d : d - E_CNT;
    int src = (d < E_CNT) ? rows[eid] : cols[eid];
    int dst = (d < E_CNT) ? cols[eid] : rows[eid];
    int pos = atomicAdd(&cursor[dst], 1);
    esrc[pos] = src;
    eeid[pos] = eid;
    wvals[pos] = dinv[src] * dinv[dst];
}

// --- edge projection: ep = ef @ W + b ---------------------------------------
// Lane k owns output column k; W column held in 64 VGPRs. Edge row staged in
// wave-private LDS (wave-synchronous write->read), read back as broadcast
// ds_read_b128 (all lanes same address = conflict-free).
__global__ __launch_bounds__(256) void ep_kernel(const float* __restrict__ ef,
                                                 const float* __restrict__ W,
                                                 const float* __restrict__ bias,
                                                 float* __restrict__ ep) {
    __shared__ __align__(16) float sE[4][F_DIM];
    int tid = threadIdx.x;
    int k = tid & 63;
    int wv = tid >> 6;
    float wreg[F_DIM];
    #pragma unroll
    for (int f = 0; f < F_DIM; f++) wreg[f] = W[f * K_DIM + k];
    float bv = bias[k];
    int e0 = blockIdx.x * 128 + wv * 32;
    for (int c = 0; c < 32; c++) {
        int e = e0 + c;
        if (e >= E_CNT) return;   // e is wave-uniform
        sE[wv][k] = ef[(size_t)e * F_DIM + k];
        float acc = bv;
        #pragma unroll
        for (int fq = 0; fq < F_DIM / 4; fq++) {
            float4 v = *(const float4*)&sE[wv][fq * 4];
            acc = fmaf(v.x, wreg[fq * 4 + 0], acc);
            acc = fmaf(v.y, wreg[fq * 4 + 1], acc);
            acc = fmaf(v.z, wreg[fq * 4 + 2], acc);
            acc = fmaf(v.w, wreg[fq * 4 + 3], acc);
        }
        ep[(size_t)e * K_DIM + k] = acc;
    }
}

// --- init fp32 tables (float4 copies) ---------------------------------------
__global__ __launch_bounds__(256) void init_kernel(const float4* __restrict__ Gu,
                                                   const float4* __restrict__ Gi,
                                                   const float4* __restrict__ Gut,
                                                   const float4* __restrict__ Git,
                                                   float4* __restrict__ C,
                                                   float4* __restrict__ T) {
    int idx = blockIdx.x * blockDim.x + threadIdx.x;
    const int UK4 = U_CNT * K_DIM / 4;
    const int NK4 = N_CNT * K_DIM / 4;
    if (idx < NK4) {
        if (idx < UK4) {
            C[idx] = Gu[idx];
            T[idx] = Gut[idx];
        } else {
            C[idx] = Gi[idx - UK4];
            T[idx] = Git[idx - UK4];
        }
    }
}

// --- one propagation layer, gather-only (no atomics) ------------------------
// Wave per destination node, lane per feature. Streaming store, no memset.
__global__ __launch_bounds__(256) void prop_kernel(const int* __restrict__ offs,
                                                   const int* __restrict__ esrc,
                                                   const int* __restrict__ eeid,
                                                   const float* __restrict__ wvals,
                                                   const float* __restrict__ ep,
                                                   const float* __restrict__ Cin,
                                                   const float* __restrict__ Tin,
                                                   float* __restrict__ Cout,
                                                   float* __restrict__ Tout) {
    int gt = blockIdx.x * blockDim.x + threadIdx.x;
    int n = gt >> 6;
    int k = threadIdx.x & 63;
    if (n >= N_CNT) return;
    int p0 = offs[n];
    int p1 = offs[n + 1];
    float accC = 0.0f, accT = 0.0f;
    for (int p = p0; p < p1; p++) {
        int s   = esrc[p];     // wave-uniform
        int eid = eeid[p];     // wave-uniform
        float w = wvals[p];    // wave-uniform
        accC = fmaf(w, Cin[(size_t)s * K_DIM + k], accC);
        accT = fmaf(w * ep[(size_t)eid * K_DIM + k], Tin[(size_t)s * K_DIM + k], accT);
    }
    Cout[(size_t)n * K_DIM + k] = accC;
    Tout[(size_t)n * K_DIM + k] = accT;
}

// --- scoring: wave per query, 64-lane shuffle reduction ---------------------
__global__ __launch_bounds__(256) void score_kernel(const int* __restrict__ users,
                                                    const int* __restrict__ items,
                                                    const float* __restrict__ C,
                                                    const float* __restrict__ T,
                                                    const float* __restrict__ Bu,
                                                    const float* __restrict__ Bi,
                                                    const float* __restrict__ But,
                                                    const float* __restrict__ Bit,
                                                    const float* __restrict__ Mu,
                                                    float* __restrict__ out) {
    int gt = blockIdx.x * blockDim.x + threadIdx.x;
    int b = gt >> 6;
    int k = threadIdx.x & 63;
    if (b >= B_CNT) return;
    int u = users[b];
    int it = items[b];
    size_t ui = (size_t)u * K_DIM + k;
    size_t ii = (size_t)(U_CNT + it) * K_DIM + k;
    float v = C[ui] * C[ii] + T[ui] * T[ii];
    #pragma unroll
    for (int off = 32; off > 0; off >>= 1) {
        v += __shfl_down(v, off, 64);
    }
    if (k == 0) {
        v += Bu[u] + Bi[it] + But[u] + Bit[it] + Mu[0];
        out[b] = v;
    }
}

extern "C" void kernel_launch(void* const* d_in, const int* in_sizes, int n_in,
                              void* d_out, int out_size, void* d_ws, size_t ws_size,
                              hipStream_t stream) {
    const float* Gu   = (const float*)d_in[0];
    const float* Gi   = (const float*)d_in[1];
    const float* Gut  = (const float*)d_in[2];
    const float* Git  = (const float*)d_in[3];
    const float* Bu   = (const float*)d_in[4];
    const float* Bi   = (const float*)d_in[5];
    const float* But  = (const float*)d_in[6];
    const float* Bit  = (const float*)d_in[7];
    const float* Mu   = (const float*)d_in[8];
    const float* W    = (const float*)d_in[9];
    const float* bpj  = (const float*)d_in[10];
    const float* ef   = (const float*)d_in[11];
    const int* rows   = (const int*)d_in[12];
    const int* cols   = (const int*)d_in[13];
    const int* users  = (const int*)d_in[14];
    const int* items  = (const int*)d_in[15];
    float* out = (float*)d_out;

    const size_t NK = (size_t)N_CNT * K_DIM;
    const size_t EK = (size_t)E_CNT * K_DIM;

    float* ws    = (float*)d_ws;
    float* ep    = ws;                 // E*K   (128 MB), 16B-aligned
    float* C0    = ep + EK;            // N*K
    float* C1    = C0 + NK;
    float* T0    = C1 + NK;
    float* T1    = T0 + NK;
    float* dinv  = T1 + NK;            // N
    float* wvals = dinv + N_CNT;       // 2E
    int* cnt     = (int*)(wvals + 2 * E_CNT);  // N
    int* offs    = cnt + N_CNT;        // N+1
    int* cursor  = offs + N_CNT + 1;   // N
    int* esrc    = cursor + N_CNT;     // 2E
    int* eeid    = esrc + 2 * E_CNT;   // 2E
    // total ~296 MB

    hipMemsetAsync(cnt, 0, N_CNT * sizeof(int), stream);
    cnt_kernel<<<(E_CNT + 255) / 256, 256, 0, stream>>>(rows, cols, cnt);
    dinv_kernel<<<(N_CNT + 255) / 256, 256, 0, stream>>>(cnt, dinv);
    scan_kernel<<<1, SCAN_T, 0, stream>>>(cnt, offs, cursor);
    scatter_kernel<<<(2 * E_CNT + 255) / 256, 256, 0, stream>>>(
        rows, cols, dinv, cursor, esrc, eeid, wvals);
    ep_kernel<<<(E_CNT + 127) / 128, 256, 0, stream>>>(ef, W, bpj, ep);
    init_kernel<<<((int)(NK / 4) + 255) / 256, 256, 0, stream>>>(
        (const float4*)Gu, (const float4*)Gi, (const float4*)Gut, (const float4*)Git,
        (float4*)C0, (float4*)T0);

    float* Cs[2] = {C0, C1};
    float* Ts[2] = {T0, T1};
    int cur = 0;
    for (int l = 0; l < N_LAYERS; l++) {
        prop_kernel<<<(N_CNT * 64 + 255) / 256, 256, 0, stream>>>(
            offs, esrc, eeid, wvals, ep, Cs[cur], Ts[cur], Cs[1 - cur], Ts[1 - cur]);
        cur = 1 - cur;
    }

    score_kernel<<<(B_CNT * 64 + 255) / 256, 256, 0, stream>>>(
        users, items, Cs[cur], Ts[cur], Bu, Bi, But, Bit, Mu, out);
}

// Round 4
// 780.756 us; speedup vs baseline: 2.5797x; 1.6407x over previous
//
#include <hip/hip_runtime.h>
#include <hip/hip_bf16.h>

#define U_CNT 100000
#define I_CNT 50000
#define N_CNT 150000   // U + I
#define K_DIM 64
#define E_CNT 500000
#define F_DIM 64
#define N_LAYERS 3
#define B_CNT 100000
#define NBLK_SCAN ((N_CNT + 255) / 256)   // 586

typedef __hip_bfloat16 bf16;

__device__ __forceinline__ float bf2f(bf16 x) { return __bfloat162float(x); }
__device__ __forceinline__ bf16 f2bf(float x) { return __float2bfloat16(x); }

// --- int degree count over both endpoints -----------------------------------
__global__ __launch_bounds__(256) void cnt_kernel(const int* __restrict__ rows,
                                                  const int* __restrict__ cols,
                                                  int* __restrict__ cnt) {
    int e = blockIdx.x * blockDim.x + threadIdx.x;
    if (e < E_CNT) {
        atomicAdd(&cnt[rows[e]], 1);
        atomicAdd(&cnt[cols[e]], 1);
    }
}

// --- dinv[n] = deg>0 ? rsqrt(deg) : 0 ---------------------------------------
__global__ __launch_bounds__(256) void dinv_kernel(const int* __restrict__ cnt,
                                                   float* __restrict__ dinv) {
    int n = blockIdx.x * blockDim.x + threadIdx.x;
    if (n < N_CNT) {
        int c = cnt[n];
        dinv[n] = (c > 0) ? rsqrtf((float)c) : 0.0f;
    }
}

// --- hierarchical exclusive scan, phase A: per-block sums -------------------
__global__ __launch_bounds__(256) void scanA_kernel(const int* __restrict__ cnt,
                                                    int* __restrict__ bsum) {
    __shared__ int sd[256];
    int tid = threadIdx.x;
    int i = blockIdx.x * 256 + tid;
    sd[tid] = (i < N_CNT) ? cnt[i] : 0;
    __syncthreads();
    for (int off = 128; off > 0; off >>= 1) {
        if (tid < off) sd[tid] += sd[tid + off];
        __syncthreads();
    }
    if (tid == 0) bsum[blockIdx.x] = sd[0];
}

// --- phase B: one block scans the 586 block sums (exclusive) ----------------
__global__ __launch_bounds__(1024) void scanB_kernel(const int* __restrict__ bsum,
                                                     int* __restrict__ boff) {
    __shared__ int sd[1024];
    int tid = threadIdx.x;
    int v = (tid < NBLK_SCAN) ? bsum[tid] : 0;
    sd[tid] = v;
    __syncthreads();
    for (int off = 1; off < 1024; off <<= 1) {
        int t = 0;
        if (tid >= off) t = sd[tid - off];
        __syncthreads();
        if (tid >= off) sd[tid] += t;
        __syncthreads();
    }
    if (tid < NBLK_SCAN) boff[tid] = sd[tid] - v;
}

// --- phase C: in-block exclusive scan + block offset -> offs/cursor ---------
__global__ __launch_bounds__(256) void scanC_kernel(const int* __restrict__ cnt,
                                                    const int* __restrict__ boff,
                                                    int* __restrict__ offs,
                                                    int* __restrict__ cursor) {
    __shared__ int sd[256];
    int tid = threadIdx.x;
    int i = blockIdx.x * 256 + tid;
    int v = (i < N_CNT) ? cnt[i] : 0;
    sd[tid] = v;
    __syncthreads();
    for (int off = 1; off < 256; off <<= 1) {
        int t = 0;
        if (tid >= off) t = sd[tid - off];
        __syncthreads();
        if (tid >= off) sd[tid] += t;
        __syncthreads();
    }
    if (i < N_CNT) {
        int ex = boff[blockIdx.x] + sd[tid] - v;
        offs[i] = ex;
        cursor[i] = ex;
    }
    if (blockIdx.x == 0 && tid == 0) offs[N_CNT] = 2 * E_CNT;
}

// --- scatter directed edges into CSR slots ----------------------------------
// Slot order nondeterministic (atomic cursor) — only perturbs fp sum order.
__global__ __launch_bounds__(256) void scatter_kernel(const int* __restrict__ rows,
                                                      const int* __restrict__ cols,
                                                      const float* __restrict__ dinv,
                                                      int* __restrict__ cursor,
                                                      int* __restrict__ esrc,
                                                      int* __restrict__ eeid,
                                                      float* __restrict__ wvals) {
    int d = blockIdx.x * blockDim.x + threadIdx.x;
    if (d >= 2 * E_CNT) return;
    int eid = (d < E_CNT) ? d : d - E_CNT;
    int src = (d < E_CNT) ? rows[eid] : cols[eid];
    int dst = (d < E_CNT) ? cols[eid] : rows[eid];
    int pos = atomicAdd(&cursor[dst], 1);
    esrc[pos] = src;
    eeid[pos] = eid;
    wvals[pos] = dinv[src] * dinv[dst];
}

// --- edge projection, norm-fused: epw = (ef @ W + b) * nrm, stored bf16 -----
// Lane k owns column k; W column in 64 VGPRs; edge row staged wave-private in
// LDS and read back as broadcast float4 (same-address = conflict-free).
__global__ __launch_bounds__(256) void ep_kernel(const float* __restrict__ ef,
                                                 const float* __restrict__ W,
                                                 const float* __restrict__ bias,
                                                 const int* __restrict__ rows,
                                                 const int* __restrict__ cols,
                                                 const float* __restrict__ dinv,
                                                 bf16* __restrict__ epw) {
    __shared__ __align__(16) float sE[4][F_DIM];
    int tid = threadIdx.x;
    int k = tid & 63;
    int wv = tid >> 6;
    float wreg[F_DIM];
    #pragma unroll
    for (int f = 0; f < F_DIM; f++) wreg[f] = W[f * K_DIM + k];
    float bv = bias[k];
    int e0 = blockIdx.x * 128 + wv * 32;
    for (int c = 0; c < 32; c++) {
        int e = e0 + c;                 // wave-uniform
        if (e >= E_CNT) return;
        float w = dinv[rows[e]] * dinv[cols[e]];
        sE[wv][k] = ef[(size_t)e * F_DIM + k];
        float acc = bv;
        #pragma unroll
        for (int fq = 0; fq < F_DIM / 4; fq++) {
            float4 v = *(const float4*)&sE[wv][fq * 4];
            acc = fmaf(v.x, wreg[fq * 4 + 0], acc);
            acc = fmaf(v.y, wreg[fq * 4 + 1], acc);
            acc = fmaf(v.z, wreg[fq * 4 + 2], acc);
            acc = fmaf(v.w, wreg[fq * 4 + 3], acc);
        }
        epw[(size_t)e * K_DIM + k] = f2bf(acc * w);
    }
}

// --- init bf16 tables: C = concat(Gu,Gi), T = concat(Gut,Git) ---------------
__global__ __launch_bounds__(256) void init_kernel(const float* __restrict__ Gu,
                                                   const float* __restrict__ Gi,
                                                   const float* __restrict__ Gut,
                                                   const float* __restrict__ Git,
                                                   bf16* __restrict__ C,
                                                   bf16* __restrict__ T) {
    int idx = blockIdx.x * blockDim.x + threadIdx.x;
    const int UK = U_CNT * K_DIM;
    const int NK = N_CNT * K_DIM;
    if (idx < NK) {
        if (idx < UK) {
            C[idx] = f2bf(Gu[idx]);
            T[idx] = f2bf(Gut[idx]);
        } else {
            C[idx] = f2bf(Gi[idx - UK]);
            T[idx] = f2bf(Git[idx - UK]);
        }
    }
}

// --- one propagation layer, gather-only, bf16 tables, fp32 accumulate -------
// Wave per destination node, lane per feature.
__global__ __launch_bounds__(256) void prop_kernel(const int* __restrict__ offs,
                                                   const int* __restrict__ esrc,
                                                   const int* __restrict__ eeid,
                                                   const float* __restrict__ wvals,
                                                   const bf16* __restrict__ epw,
                                                   const bf16* __restrict__ Cin,
                                                   const bf16* __restrict__ Tin,
                                                   bf16* __restrict__ Cout,
                                                   bf16* __restrict__ Tout) {
    int gt = blockIdx.x * blockDim.x + threadIdx.x;
    int n = __builtin_amdgcn_readfirstlane(gt >> 6);   // wave-uniform -> SGPR
    int k = threadIdx.x & 63;
    if (n >= N_CNT) return;
    int p0 = offs[n];
    int p1 = offs[n + 1];
    float accC = 0.0f, accT = 0.0f;
    for (int p = p0; p < p1; p++) {
        int s   = esrc[p];     // wave-uniform scalar loads
        int eid = eeid[p];
        float w = wvals[p];
        accC = fmaf(w, bf2f(Cin[(size_t)s * K_DIM + k]), accC);
        accT = fmaf(bf2f(epw[(size_t)eid * K_DIM + k]),
                    bf2f(Tin[(size_t)s * K_DIM + k]), accT);
    }
    Cout[(size_t)n * K_DIM + k] = f2bf(accC);
    Tout[(size_t)n * K_DIM + k] = f2bf(accT);
}

// --- scoring: wave per query, 64-lane shuffle reduction ---------------------
__global__ __launch_bounds__(256) void score_kernel(const int* __restrict__ users,
                                                    const int* __restrict__ items,
                                                    const bf16* __restrict__ C,
                                                    const bf16* __restrict__ T,
                                                    const float* __restrict__ Bu,
                                                    const float* __restrict__ Bi,
                                                    const float* __restrict__ But,
                                                    const float* __restrict__ Bit,
                                                    const float* __restrict__ Mu,
                                                    float* __restrict__ out) {
    int gt = blockIdx.x * blockDim.x + threadIdx.x;
    int b = __builtin_amdgcn_readfirstlane(gt >> 6);
    int k = threadIdx.x & 63;
    if (b >= B_CNT) return;
    int u = users[b];
    int it = items[b];
    size_t ui = (size_t)u * K_DIM + k;
    size_t ii = (size_t)(U_CNT + it) * K_DIM + k;
    float v = bf2f(C[ui]) * bf2f(C[ii]) + bf2f(T[ui]) * bf2f(T[ii]);
    #pragma unroll
    for (int off = 32; off > 0; off >>= 1) {
        v += __shfl_down(v, off, 64);
    }
    if (k == 0) {
        v += Bu[u] + Bi[it] + But[u] + Bit[it] + Mu[0];
        out[b] = v;
    }
}

extern "C" void kernel_launch(void* const* d_in, const int* in_sizes, int n_in,
                              void* d_out, int out_size, void* d_ws, size_t ws_size,
                              hipStream_t stream) {
    const float* Gu   = (const float*)d_in[0];
    const float* Gi   = (const float*)d_in[1];
    const float* Gut  = (const float*)d_in[2];
    const float* Git  = (const float*)d_in[3];
    const float* Bu   = (const float*)d_in[4];
    const float* Bi   = (const float*)d_in[5];
    const float* But  = (const float*)d_in[6];
    const float* Bit  = (const float*)d_in[7];
    const float* Mu   = (const float*)d_in[8];
    const float* W    = (const float*)d_in[9];
    const float* bpj  = (const float*)d_in[10];
    const float* ef   = (const float*)d_in[11];
    const int* rows   = (const int*)d_in[12];
    const int* cols   = (const int*)d_in[13];
    const int* users  = (const int*)d_in[14];
    const int* items  = (const int*)d_in[15];
    float* out = (float*)d_out;

    const size_t NK = (size_t)N_CNT * K_DIM;
    const size_t EK = (size_t)E_CNT * K_DIM;

    // 256B-aligned bump allocator over d_ws (~155 MB total)
    char* wp = (char*)d_ws;
    auto alloc = [&](size_t bytes) {
        char* r = wp;
        wp += (bytes + 255) & ~(size_t)255;
        return r;
    };
    bf16* epw    = (bf16*)alloc(EK * sizeof(bf16));          // 64 MB
    bf16* C0     = (bf16*)alloc(NK * sizeof(bf16));          // 19.2 MB
    bf16* C1     = (bf16*)alloc(NK * sizeof(bf16));
    bf16* T0     = (bf16*)alloc(NK * sizeof(bf16));
    bf16* T1     = (bf16*)alloc(NK * sizeof(bf16));
    float* dinv  = (float*)alloc(N_CNT * sizeof(float));
    float* wvals = (float*)alloc(2 * E_CNT * sizeof(float)); // 4 MB
    int* cnt     = (int*)alloc(N_CNT * sizeof(int));
    int* offs    = (int*)alloc((N_CNT + 1) * sizeof(int));
    int* cursor  = (int*)alloc(N_CNT * sizeof(int));
    int* esrc    = (int*)alloc(2 * E_CNT * sizeof(int));     // 4 MB
    int* eeid    = (int*)alloc(2 * E_CNT * sizeof(int));     // 4 MB
    int* bsum    = (int*)alloc(NBLK_SCAN * sizeof(int));
    int* boff    = (int*)alloc(NBLK_SCAN * sizeof(int));

    hipMemsetAsync(cnt, 0, N_CNT * sizeof(int), stream);
    cnt_kernel<<<(E_CNT + 255) / 256, 256, 0, stream>>>(rows, cols, cnt);
    dinv_kernel<<<(N_CNT + 255) / 256, 256, 0, stream>>>(cnt, dinv);
    scanA_kernel<<<NBLK_SCAN, 256, 0, stream>>>(cnt, bsum);
    scanB_kernel<<<1, 1024, 0, stream>>>(bsum, boff);
    scanC_kernel<<<NBLK_SCAN, 256, 0, stream>>>(cnt, boff, offs, cursor);
    scatter_kernel<<<(2 * E_CNT + 255) / 256, 256, 0, stream>>>(
        rows, cols, dinv, cursor, esrc, eeid, wvals);
    ep_kernel<<<(E_CNT + 127) / 128, 256, 0, stream>>>(ef, W, bpj, rows, cols, dinv, epw);
    init_kernel<<<((int)NK + 255) / 256, 256, 0, stream>>>(Gu, Gi, Gut, Git, C0, T0);

    bf16* Cs[2] = {C0, C1};
    bf16* Ts[2] = {T0, T1};
    int cur = 0;
    for (int l = 0; l < N_LAYERS; l++) {
        prop_kernel<<<(N_CNT * 64 + 255) / 256, 256, 0, stream>>>(
            offs, esrc, eeid, wvals, epw, Cs[cur], Ts[cur], Cs[1 - cur], Ts[1 - cur]);
        cur = 1 - cur;
    }

    score_kernel<<<(B_CNT * 64 + 255) / 256, 256, 0, stream>>>(
        users, items, Cs[cur], Ts[cur], Bu, Bi, But, Bit, Mu, out);
}

// Round 5
// 635.298 us; speedup vs baseline: 3.1704x; 1.2290x over previous
//
#include <hip/hip_runtime.h>
#include <hip/hip_bf16.h>

#define U_CNT 100000
#define I_CNT 50000
#define N_CNT 150000   // U + I
#define K_DIM 64
#define E_CNT 500000
#define F_DIM 64
#define N_LAYERS 3
#define B_CNT 100000
#define NBLK_SCAN ((N_CNT + 255) / 256)   // 586
#define EP_TILES (E_CNT / 16)             // 31250 (exact)
#define EP_BLOCKS 512

typedef __hip_bfloat16 bf16;
typedef __attribute__((ext_vector_type(8))) short short8;
typedef __attribute__((ext_vector_type(4))) float f32x4;

__device__ __forceinline__ float u2f(unsigned short u) {
    return __uint_as_float(((unsigned)u) << 16);
}
__device__ __forceinline__ unsigned short f2u(float x) {
    bf16 h = __float2bfloat16(x);           // RNE
    return *reinterpret_cast<unsigned short*>(&h);
}

// --- int degree count over both endpoints -----------------------------------
__global__ __launch_bounds__(256) void cnt_kernel(const int* __restrict__ rows,
                                                  const int* __restrict__ cols,
                                                  int* __restrict__ cnt) {
    int e = blockIdx.x * blockDim.x + threadIdx.x;
    if (e < E_CNT) {
        atomicAdd(&cnt[rows[e]], 1);
        atomicAdd(&cnt[cols[e]], 1);
    }
}

// --- dinv[n] = deg>0 ? rsqrt(deg) : 0 ---------------------------------------
__global__ __launch_bounds__(256) void dinv_kernel(const int* __restrict__ cnt,
                                                   float* __restrict__ dinv) {
    int n = blockIdx.x * blockDim.x + threadIdx.x;
    if (n < N_CNT) {
        int c = cnt[n];
        dinv[n] = (c > 0) ? rsqrtf((float)c) : 0.0f;
    }
}

// --- hierarchical exclusive scan --------------------------------------------
__global__ __launch_bounds__(256) void scanA_kernel(const int* __restrict__ cnt,
                                                    int* __restrict__ bsum) {
    __shared__ int sd[256];
    int tid = threadIdx.x;
    int i = blockIdx.x * 256 + tid;
    sd[tid] = (i < N_CNT) ? cnt[i] : 0;
    __syncthreads();
    for (int off = 128; off > 0; off >>= 1) {
        if (tid < off) sd[tid] += sd[tid + off];
        __syncthreads();
    }
    if (tid == 0) bsum[blockIdx.x] = sd[0];
}

__global__ __launch_bounds__(1024) void scanB_kernel(const int* __restrict__ bsum,
                                                     int* __restrict__ boff) {
    __shared__ int sd[1024];
    int tid = threadIdx.x;
    int v = (tid < NBLK_SCAN) ? bsum[tid] : 0;
    sd[tid] = v;
    __syncthreads();
    for (int off = 1; off < 1024; off <<= 1) {
        int t = 0;
        if (tid >= off) t = sd[tid - off];
        __syncthreads();
        if (tid >= off) sd[tid] += t;
        __syncthreads();
    }
    if (tid < NBLK_SCAN) boff[tid] = sd[tid] - v;
}

__global__ __launch_bounds__(256) void scanC_kernel(const int* __restrict__ cnt,
                                                    const int* __restrict__ boff,
                                                    int* __restrict__ offs,
                                                    int* __restrict__ cursor) {
    __shared__ int sd[256];
    int tid = threadIdx.x;
    int i = blockIdx.x * 256 + tid;
    int v = (i < N_CNT) ? cnt[i] : 0;
    sd[tid] = v;
    __syncthreads();
    for (int off = 1; off < 256; off <<= 1) {
        int t = 0;
        if (tid >= off) t = sd[tid - off];
        __syncthreads();
        if (tid >= off) sd[tid] += t;
        __syncthreads();
    }
    if (i < N_CNT) {
        int ex = boff[blockIdx.x] + sd[tid] - v;
        offs[i] = ex;
        cursor[i] = ex;
    }
    if (blockIdx.x == 0 && tid == 0) offs[N_CNT] = 2 * E_CNT;
}

// --- scatter directed edges into CSR slots ----------------------------------
__global__ __launch_bounds__(256) void scatter_kernel(const int* __restrict__ rows,
                                                      const int* __restrict__ cols,
                                                      const float* __restrict__ dinv,
                                                      int* __restrict__ cursor,
                                                      int* __restrict__ esrc,
                                                      int* __restrict__ eeid,
                                                      float* __restrict__ wvals) {
    int d = blockIdx.x * blockDim.x + threadIdx.x;
    if (d >= 2 * E_CNT) return;
    int eid = (d < E_CNT) ? d : d - E_CNT;
    int src = (d < E_CNT) ? rows[eid] : cols[eid];
    int dst = (d < E_CNT) ? cols[eid] : rows[eid];
    int pos = atomicAdd(&cursor[dst], 1);
    esrc[pos] = src;
    eeid[pos] = eid;
    wvals[pos] = dinv[src] * dinv[dst];
}

// --- edge projection via MFMA: epw = (ef @ W + b) * nrm, bf16 ---------------
// 16-edge x 64-col tiles; K=F=64 as 2 mfma_f32_16x16x32_bf16 steps.
// A-frag: A[m=lane&15][k=quad*8+j] -> 32B contiguous load per lane from ef.
// B-frag (W): B[k=quad*8+j][n=lane&15], loaded once per wave, reused ~15 tiles.
// C/D: row = quad*4+reg, col = lane&15 (m89-verified layout).
__global__ __launch_bounds__(256) void ep_kernel(const float* __restrict__ ef,
                                                 const float* __restrict__ W,
                                                 const float* __restrict__ bias,
                                                 const int* __restrict__ rows,
                                                 const int* __restrict__ cols,
                                                 const float* __restrict__ dinv,
                                                 bf16* __restrict__ epw) {
    int lane = threadIdx.x & 63;
    int wv = threadIdx.x >> 6;
    int m15 = lane & 15;
    int quad = lane >> 4;

    short8 bfrag[2][4];
    #pragma unroll
    for (int s = 0; s < 2; s++) {
        #pragma unroll
        for (int t = 0; t < 4; t++) {
            short8 b;
            #pragma unroll
            for (int j = 0; j < 8; j++) {
                int f = s * 32 + quad * 8 + j;
                b[j] = (short)f2u(W[f * K_DIM + t * 16 + m15]);
            }
            bfrag[s][t] = b;
        }
    }
    float bv[4];
    #pragma unroll
    for (int t = 0; t < 4; t++) bv[t] = bias[t * 16 + m15];

    for (int tile = blockIdx.x * 4 + wv; tile < EP_TILES; tile += EP_BLOCKS * 4) {
        int e0 = tile * 16;
        // norm for the 16 edges, computed in lanes 0..15, broadcast to rows
        float wlane = 0.0f;
        if (lane < 16) {
            int e = e0 + lane;
            wlane = dinv[rows[e]] * dinv[cols[e]];
        }
        float wrow[4];
        #pragma unroll
        for (int r = 0; r < 4; r++) wrow[r] = __shfl(wlane, quad * 4 + r, 64);

        short8 afrag[2];
        #pragma unroll
        for (int s = 0; s < 2; s++) {
            const float* src = ef + (size_t)(e0 + m15) * F_DIM + s * 32 + quad * 8;
            float4 lo = *(const float4*)src;
            float4 hi = *(const float4*)(src + 4);
            short8 a;
            a[0] = (short)f2u(lo.x); a[1] = (short)f2u(lo.y);
            a[2] = (short)f2u(lo.z); a[3] = (short)f2u(lo.w);
            a[4] = (short)f2u(hi.x); a[5] = (short)f2u(hi.y);
            a[6] = (short)f2u(hi.z); a[7] = (short)f2u(hi.w);
            afrag[s] = a;
        }

        f32x4 acc[4];
        #pragma unroll
        for (int t = 0; t < 4; t++) acc[t] = (f32x4){0.0f, 0.0f, 0.0f, 0.0f};
        #pragma unroll
        for (int s = 0; s < 2; s++) {
            #pragma unroll
            for (int t = 0; t < 4; t++) {
                acc[t] = __builtin_amdgcn_mfma_f32_16x16x32_bf16(
                    afrag[s], bfrag[s][t], acc[t], 0, 0, 0);
            }
        }
        #pragma unroll
        for (int t = 0; t < 4; t++) {
            #pragma unroll
            for (int r = 0; r < 4; r++) {
                int e = e0 + quad * 4 + r;
                float v = (acc[t][r] + bv[t]) * wrow[r];
                epw[(size_t)e * K_DIM + t * 16 + m15] = __float2bfloat16(v);
            }
        }
    }
}

// --- init bf16 tables, vectorized -------------------------------------------
__global__ __launch_bounds__(256) void init_kernel(const float4* __restrict__ Gu,
                                                   const float4* __restrict__ Gi,
                                                   const float4* __restrict__ Gut,
                                                   const float4* __restrict__ Git,
                                                   ushort4* __restrict__ C,
                                                   ushort4* __restrict__ T) {
    int idx = blockIdx.x * blockDim.x + threadIdx.x;
    const int UK4 = U_CNT * K_DIM / 4;
    const int NK4 = N_CNT * K_DIM / 4;
    if (idx >= NK4) return;
    float4 c = (idx < UK4) ? Gu[idx] : Gi[idx - UK4];
    float4 t = (idx < UK4) ? Gut[idx] : Git[idx - UK4];
    ushort4 co, to;
    co.x = f2u(c.x); co.y = f2u(c.y); co.z = f2u(c.z); co.w = f2u(c.w);
    to.x = f2u(t.x); to.y = f2u(t.y); to.z = f2u(t.z); to.w = f2u(t.w);
    C[idx] = co;
    T[idx] = to;
}

// --- one propagation layer: 4 edges per iteration ---------------------------
// Wave per destination node; lane = (sub = lane>>4 edge-in-quad, q = lane&15
// col-chunk of 4 bf16). ushort4 (8B) gathers; cross-sub shuffle reduction.
__global__ __launch_bounds__(256) void prop_kernel(const int* __restrict__ offs,
                                                   const int* __restrict__ esrc,
                                                   const int* __restrict__ eeid,
                                                   const float* __restrict__ wvals,
                                                   const bf16* __restrict__ epw,
                                                   const bf16* __restrict__ Cin,
                                                   const bf16* __restrict__ Tin,
                                                   bf16* __restrict__ Cout,
                                                   bf16* __restrict__ Tout) {
    int gt = blockIdx.x * blockDim.x + threadIdx.x;
    int n = gt >> 6;
    if (n >= N_CNT) return;
    int lane = threadIdx.x & 63;
    int sub = lane >> 4;
    int q = lane & 15;
    int p0 = offs[n];
    int p1 = offs[n + 1];
    float accC[4] = {0.0f, 0.0f, 0.0f, 0.0f};
    float accT[4] = {0.0f, 0.0f, 0.0f, 0.0f};
    for (int p = p0; p < p1; p += 4) {
        int pe = p + sub;
        if (pe < p1) {
            int s   = esrc[pe];
            int eid = eeid[pe];
            float w = wvals[pe];
            ushort4 cv = *(const ushort4*)((const unsigned short*)Cin + ((size_t)s << 6) + (q << 2));
            ushort4 tv = *(const ushort4*)((const unsigned short*)Tin + ((size_t)s << 6) + (q << 2));
            ushort4 ev = *(const ushort4*)((const unsigned short*)epw + ((size_t)eid << 6) + (q << 2));
            accC[0] = fmaf(w, u2f(cv.x), accC[0]);
            accC[1] = fmaf(w, u2f(cv.y), accC[1]);
            accC[2] = fmaf(w, u2f(cv.z), accC[2]);
            accC[3] = fmaf(w, u2f(cv.w), accC[3]);
            accT[0] = fmaf(u2f(ev.x), u2f(tv.x), accT[0]);
            accT[1] = fmaf(u2f(ev.y), u2f(tv.y), accT[1]);
            accT[2] = fmaf(u2f(ev.z), u2f(tv.z), accT[2]);
            accT[3] = fmaf(u2f(ev.w), u2f(tv.w), accT[3]);
        }
    }
    #pragma unroll
    for (int i = 0; i < 4; i++) {
        accC[i] += __shfl_down(accC[i], 32, 64);
        accC[i] += __shfl_down(accC[i], 16, 64);
        accT[i] += __shfl_down(accT[i], 32, 64);
        accT[i] += __shfl_down(accT[i], 16, 64);
    }
    if (lane < 16) {
        ushort4 oc, ot;
        oc.x = f2u(accC[0]); oc.y = f2u(accC[1]);
        oc.z = f2u(accC[2]); oc.w = f2u(accC[3]);
        ot.x = f2u(accT[0]); ot.y = f2u(accT[1]);
        ot.z = f2u(accT[2]); ot.w = f2u(accT[3]);
        *(ushort4*)((unsigned short*)Cout + ((size_t)n << 6) + (q << 2)) = oc;
        *(ushort4*)((unsigned short*)Tout + ((size_t)n << 6) + (q << 2)) = ot;
    }
}

// --- scoring: wave per query, 64-lane shuffle reduction ---------------------
__global__ __launch_bounds__(256) void score_kernel(const int* __restrict__ users,
                                                    const int* __restrict__ items,
                                                    const bf16* __restrict__ C,
                                                    const bf16* __restrict__ T,
                                                    const float* __restrict__ Bu,
                                                    const float* __restrict__ Bi,
                                                    const float* __restrict__ But,
                                                    const float* __restrict__ Bit,
                                                    const float* __restrict__ Mu,
                                                    float* __restrict__ out) {
    int gt = blockIdx.x * blockDim.x + threadIdx.x;
    int b = gt >> 6;
    int k = threadIdx.x & 63;
    if (b >= B_CNT) return;
    int u = users[b];
    int it = items[b];
    size_t ui = (size_t)u * K_DIM + k;
    size_t ii = (size_t)(U_CNT + it) * K_DIM + k;
    float v = __bfloat162float(C[ui]) * __bfloat162float(C[ii])
            + __bfloat162float(T[ui]) * __bfloat162float(T[ii]);
    #pragma unroll
    for (int off = 32; off > 0; off >>= 1) {
        v += __shfl_down(v, off, 64);
    }
    if (k == 0) {
        v += Bu[u] + Bi[it] + But[u] + Bit[it] + Mu[0];
        out[b] = v;
    }
}

extern "C" void kernel_launch(void* const* d_in, const int* in_sizes, int n_in,
                              void* d_out, int out_size, void* d_ws, size_t ws_size,
                              hipStream_t stream) {
    const float* Gu   = (const float*)d_in[0];
    const float* Gi   = (const float*)d_in[1];
    const float* Gut  = (const float*)d_in[2];
    const float* Git  = (const float*)d_in[3];
    const float* Bu   = (const float*)d_in[4];
    const float* Bi   = (const float*)d_in[5];
    const float* But  = (const float*)d_in[6];
    const float* Bit  = (const float*)d_in[7];
    const float* Mu   = (const float*)d_in[8];
    const float* W    = (const float*)d_in[9];
    const float* bpj  = (const float*)d_in[10];
    const float* ef   = (const float*)d_in[11];
    const int* rows   = (const int*)d_in[12];
    const int* cols   = (const int*)d_in[13];
    const int* users  = (const int*)d_in[14];
    const int* items  = (const int*)d_in[15];
    float* out = (float*)d_out;

    const size_t NK = (size_t)N_CNT * K_DIM;
    const size_t EK = (size_t)E_CNT * K_DIM;

    char* wp = (char*)d_ws;
    auto alloc = [&](size_t bytes) {
        char* r = wp;
        wp += (bytes + 255) & ~(size_t)255;
        return r;
    };
    bf16* epw    = (bf16*)alloc(EK * sizeof(bf16));          // 64 MB
    bf16* C0     = (bf16*)alloc(NK * sizeof(bf16));          // 19.2 MB
    bf16* C1     = (bf16*)alloc(NK * sizeof(bf16));
    bf16* T0     = (bf16*)alloc(NK * sizeof(bf16));
    bf16* T1     = (bf16*)alloc(NK * sizeof(bf16));
    float* dinv  = (float*)alloc(N_CNT * sizeof(float));
    float* wvals = (float*)alloc(2 * E_CNT * sizeof(float));
    int* cnt     = (int*)alloc(N_CNT * sizeof(int));
    int* offs    = (int*)alloc((N_CNT + 1) * sizeof(int));
    int* cursor  = (int*)alloc(N_CNT * sizeof(int));
    int* esrc    = (int*)alloc(2 * E_CNT * sizeof(int));
    int* eeid    = (int*)alloc(2 * E_CNT * sizeof(int));
    int* bsum    = (int*)alloc(NBLK_SCAN * sizeof(int));
    int* boff    = (int*)alloc(NBLK_SCAN * sizeof(int));

    hipMemsetAsync(cnt, 0, N_CNT * sizeof(int), stream);
    cnt_kernel<<<(E_CNT + 255) / 256, 256, 0, stream>>>(rows, cols, cnt);
    dinv_kernel<<<(N_CNT + 255) / 256, 256, 0, stream>>>(cnt, dinv);
    scanA_kernel<<<NBLK_SCAN, 256, 0, stream>>>(cnt, bsum);
    scanB_kernel<<<1, 1024, 0, stream>>>(bsum, boff);
    scanC_kernel<<<NBLK_SCAN, 256, 0, stream>>>(cnt, boff, offs, cursor);
    scatter_kernel<<<(2 * E_CNT + 255) / 256, 256, 0, stream>>>(
        rows, cols, dinv, cursor, esrc, eeid, wvals);
    ep_kernel<<<EP_BLOCKS, 256, 0, stream>>>(ef, W, bpj, rows, cols, dinv, epw);
    init_kernel<<<((int)(NK / 4) + 255) / 256, 256, 0, stream>>>(
        (const float4*)Gu, (const float4*)Gi, (const float4*)Gut, (const float4*)Git,
        (ushort4*)C0, (ushort4*)T0);

    bf16* Cs[2] = {C0, C1};
    bf16* Ts[2] = {T0, T1};
    int cur = 0;
    for (int l = 0; l < N_LAYERS; l++) {
        prop_kernel<<<(N_CNT * 64 + 255) / 256, 256, 0, stream>>>(
            offs, esrc, eeid, wvals, epw, Cs[cur], Ts[cur], Cs[1 - cur], Ts[1 - cur]);
        cur = 1 - cur;
    }

    score_kernel<<<(B_CNT * 64 + 255) / 256, 256, 0, stream>>>(
        users, items, Cs[cur], Ts[cur], Bu, Bi, But, Bit, Mu, out);
}